// Round 20
// baseline (784.075 us; speedup 1.0000x reference)
//
#include <hip/hip_runtime.h>
#include <hip/hip_bf16.h>

using bf16 = __hip_bfloat16;
typedef __attribute__((ext_vector_type(8))) short bf16x8;
typedef __attribute__((ext_vector_type(4))) float f32x4;

#define MFMA_BF16_16x16x32 __builtin_amdgcn_mfma_f32_16x16x32_bf16

__device__ __forceinline__ float bits2f(short b) {
  unsigned u = ((unsigned)(unsigned short)b) << 16;
  return __uint_as_float(u);
}
__device__ __forceinline__ short f2bits(float f) {
  bf16 h = __float2bfloat16(f);
  return *reinterpret_cast<short*>(&h);
}

// bijective XCD swizzle for nwg % 8 == 0
__device__ __forceinline__ int xcd_swz(int bid, int nwg) {
  int q = nwg >> 3;
  return (bid & 7) * q + (bid >> 3);
}

// LDS bank swizzle (involution: source bits 9:7, target bits 6:4 -- disjoint).
// Measured 0 bank conflicts on this 64B-row geometry (r7/r9/r12/r13/r16-r19).
__device__ __forceinline__ int bank_swz(int off) {
  return off ^ (((off >> 7) & 7) << 4);
}

// ---------------- input-dtype detection (flag=1 -> inputs are f32) ----------------
__global__ void detect_kernel(const unsigned short* __restrict__ w, int* __restrict__ flag) {
  __shared__ int bad;
  if (threadIdx.x == 0) bad = 0;
  __syncthreads();
  float m = 0.f;
#pragma unroll
  for (int j = 0; j < 4; ++j)
    m = fmaxf(m, fabsf(bits2f((short)w[threadIdx.x * 4 + j])));
  if (m > 4.0f) atomicOr(&bad, 1);
  __syncthreads();
  if (threadIdx.x == 0) *flag = bad ? 1 : 0;
}

// ---------------- positional encoding table (16 x 512, f32) ----------------
__global__ void pe_kernel(float* __restrict__ pe) {
  int s = blockIdx.x;
  int i = threadIdx.x;
  float dv = expf((float)(2 * i) * (-9.210340371976184f / 512.0f)); // -ln(10000)/512
  float ang = (float)s * dv;
  pe[s * 512 + 2 * i]     = sinf(ang);
  pe[s * 512 + 2 * i + 1] = cosf(ang);
}

// ---------------- x = enc + pe; enc base passed in both dtype interpretations ----------------
__global__ __launch_bounds__(256) void add_pe2_kernel(const void* __restrict__ enc_bf,
                                                      const void* __restrict__ enc_f32,
                                                      const float* __restrict__ pe,
                                                      bf16* __restrict__ x,
                                                      const int* __restrict__ flag) {
  size_t i = ((size_t)blockIdx.x * 256 + threadIdx.x) * 8;
  int col  = (int)(i & 511);
  int srow = (int)((i >> 9) & 15);
  float e[8];
  if (*flag) {
    const float* ef = (const float*)enc_f32 + i;
    f32x4 a = *reinterpret_cast<const f32x4*>(ef);
    f32x4 b = *reinterpret_cast<const f32x4*>(ef + 4);
#pragma unroll
    for (int j = 0; j < 4; ++j) { e[j] = a[j]; e[4 + j] = b[j]; }
  } else {
    bf16x8 ev = *reinterpret_cast<const bf16x8*>((const bf16*)enc_bf + i);
#pragma unroll
    for (int j = 0; j < 8; ++j) e[j] = bits2f(ev[j]);
  }
  const float* pp = pe + srow * 512 + col;
  f32x4 p0 = *reinterpret_cast<const f32x4*>(pp);
  f32x4 p1 = *reinterpret_cast<const f32x4*>(pp + 4);
  bf16x8 o;
#pragma unroll
  for (int j = 0; j < 4; ++j) o[j] = f2bits(e[j] + p0[j]);
#pragma unroll
  for (int j = 0; j < 4; ++j) o[4 + j] = f2bits(e[4 + j] + p1[j]);
  *reinterpret_cast<bf16x8*>(x + i) = o;
}

// ---------------- batched transpose + cvt: 6 weight matrices in ONE launch ----------------
struct TSeg { const void* src; unsigned short* dst; int R, C, base; };
struct TArgs { TSeg seg[6]; int nseg; };
__global__ __launch_bounds__(256) void transpose_all_kernel(TArgs a, const int* __restrict__ flag) {
  __shared__ unsigned short t[32][33];
  int bid = blockIdx.x;
  TSeg s = a.seg[0];
#pragma unroll
  for (int k = 1; k < 6; ++k)
    if (bid >= a.seg[k].base) s = a.seg[k];
  int local = bid - s.base;
  int nbx = s.C >> 5;
  int bx = (local % nbx) * 32;
  int by = (local / nbx) * 32;
  int lx = threadIdx.x & 31, ly = threadIdx.x >> 5;
  if (*flag) {
    const float* sp = (const float*)s.src;
#pragma unroll
    for (int i = 0; i < 4; ++i)
      t[ly + i * 8][lx] = (unsigned short)f2bits(sp[(size_t)(by + ly + i * 8) * s.C + bx + lx]);
  } else {
    const unsigned short* sp = (const unsigned short*)s.src;
#pragma unroll
    for (int i = 0; i < 4; ++i)
      t[ly + i * 8][lx] = sp[(size_t)(by + ly + i * 8) * s.C + bx + lx];
  }
  __syncthreads();
#pragma unroll
  for (int i = 0; i < 4; ++i)
    s.dst[(size_t)(bx + ly + i * 8) * s.R + by + lx] = t[lx][ly + i * 8];
}

// ---------------- batched small-vector convert ----------------
struct SmallSeg { const void* src; bf16* dst; int n; };
struct SmallCvtArgs { SmallSeg seg[11]; };
__global__ __launch_bounds__(256) void small_cvt_kernel(SmallCvtArgs a, const int* __restrict__ flag) {
  SmallSeg s = a.seg[blockIdx.x];
  int f = *flag;
  for (int i = threadIdx.x; i < s.n; i += 256) {
    float v = f ? ((const float*)s.src)[i] : bits2f(((const short*)s.src)[i]);
    s.dst[i] = __float2bfloat16(v);
  }
}

// ---------------- 256x256 GEMM, BK=32, 1024 thr, QUAD-buffered LDS, 1 barrier / 2 steps ----
// C[M,N] = A[M,K] @ Bt[N,K]^T + bias; EPI: 0=bias, 1=bias+relu, 2=bias+residual.
// 1024 thr = 16 waves (4M x 4N), per-wave 64x64 (acc 64). LDS 4 x 32 KB = 128 KiB ->
// 1 block/CU, 16 waves (same TLP as r19 which measured FFN2 188us / MfmaUtil 31%).
// vs r19: TWO K-tiles per sync quantum -> barrier+wait count HALVED per MFMA.
// Iteration i (tiles 2i, 2i+1):
//   reads(2i) from buf (2i)&3   ; stage(2i+2) -> buf (2i+2)&3 ; 16 MFMA
//   reads(2i+1) from buf (2i+1)&3; stage(2i+3) -> buf (2i+3)&3 ; 16 MFMA
//   lgkm(0); vmcnt(0) (drain -- loads issued ~2500cyc of MFMA earlier, latency hidden);
//   ONE barrier.
// Hazards: stage targets (2i+2)&3,(2i+3)&3 are exactly the two buffers read in
// iteration i-1, whose reads completed before its barrier (lgkm(0) precedes it);
// stage targets are disjoint from both in-iteration read buffers. Race-free.
template <int EPI>
__global__ __launch_bounds__(1024, 4)
void gemm20_kernel(const bf16* __restrict__ A, const bf16* __restrict__ Bt,
                   const bf16* __restrict__ bias, const bf16* res,
                   bf16* C, int M, int N, int K) {
  __shared__ __align__(16) char lds[4][32768];   // per buf: A 16K + B 16K; 128 KiB
  const int nbn = N >> 8;
  const int wg = xcd_swz(blockIdx.x, gridDim.x);
  const int bn = wg % nbn, bm = wg / nbn;
  const int m0 = bm << 8, n0 = bn << 8;
  const int tid = threadIdx.x, lane = tid & 63, wid = tid >> 6;
  const int wr = wid >> 2, wc = wid & 3;
  const int lr = lane & 15, gq = lane >> 4;
  const int nt = K >> 5;                          // 16 (K=512) or 64 (K=2048): even

  f32x4 acc[4][4] = {};
  bf16x8 a[4], b[4];

  auto stage = [&](int s, int buf) {
    {                                             // A tile: 16 KB, 1 load/thread
      int p = tid * 16;
      int q = bank_swz(p);
      const bf16* src = A + (size_t)(m0 + (q >> 6)) * K + s * 32 + ((q & 63) >> 1);
      __builtin_amdgcn_global_load_lds(
          (const __attribute__((address_space(1))) void*)src,
          (__attribute__((address_space(3))) void*)&lds[buf][wid * 1024], 16, 0, 0);
    }
    {                                             // B tile: 16 KB, 1 load/thread
      int p = tid * 16;
      int q = bank_swz(p);
      const bf16* src = Bt + (size_t)(n0 + (q >> 6)) * K + s * 32 + ((q & 63) >> 1);
      __builtin_amdgcn_global_load_lds(
          (const __attribute__((address_space(1))) void*)src,
          (__attribute__((address_space(3))) void*)&lds[buf][16384 + wid * 1024], 16, 0, 0);
    }
  };

  auto rdA = [&](int buf, int row) -> bf16x8 {
    int off = bank_swz(row * 64 + gq * 16);
    return *reinterpret_cast<const bf16x8*>(&lds[buf][off]);
  };
  auto rdB = [&](int buf, int row) -> bf16x8 {
    int off = bank_swz(row * 64 + gq * 16);
    return *reinterpret_cast<const bf16x8*>(&lds[buf][16384 + off]);
  };

  // prologue: tiles 0,1 into bufs 0,1; drain; barrier.
  stage(0, 0); stage(1, 1);
  asm volatile("s_waitcnt vmcnt(0)" ::: "memory");
  __builtin_amdgcn_s_barrier();

  for (int t = 0; t < nt; t += 2) {
    const int b0 = t & 3, b1 = (t + 1) & 3;
    const bool st = (t + 2 < nt);
    // ---- sub-step A: tile t
#pragma unroll
    for (int mf = 0; mf < 4; ++mf) a[mf] = rdA(b0, wr * 64 + mf * 16 + lr);
#pragma unroll
    for (int nf = 0; nf < 4; ++nf) b[nf] = rdB(b0, wc * 64 + nf * 16 + lr);
    if (st) stage(t + 2, (t + 2) & 3);            // buf read in prev iteration: done
    __builtin_amdgcn_s_setprio(1);
#pragma unroll
    for (int mf = 0; mf < 4; ++mf)
#pragma unroll
      for (int nf = 0; nf < 4; ++nf)
        acc[mf][nf] = MFMA_BF16_16x16x32(a[mf], b[nf], acc[mf][nf], 0, 0, 0);
    __builtin_amdgcn_s_setprio(0);
    // ---- sub-step B: tile t+1
#pragma unroll
    for (int mf = 0; mf < 4; ++mf) a[mf] = rdA(b1, wr * 64 + mf * 16 + lr);
#pragma unroll
    for (int nf = 0; nf < 4; ++nf) b[nf] = rdB(b1, wc * 64 + nf * 16 + lr);
    if (st) stage(t + 3, (t + 3) & 3);            // buf read in prev iteration: done
    __builtin_amdgcn_s_setprio(1);
#pragma unroll
    for (int mf = 0; mf < 4; ++mf)
#pragma unroll
      for (int nf = 0; nf < 4; ++nf)
        acc[mf][nf] = MFMA_BF16_16x16x32(a[mf], b[nf], acc[mf][nf], 0, 0, 0);
    __builtin_amdgcn_s_setprio(0);
    // ---- one sync quantum per 2 tiles
    asm volatile("s_waitcnt lgkmcnt(0)" ::: "memory");  // reads consumed; fences DS
    asm volatile("s_waitcnt vmcnt(0)" ::: "memory");    // tiles t+2,t+3 landed
    __builtin_amdgcn_s_barrier();
  }

  // epilogue: per-wave 64x64
#pragma unroll
  for (int mf = 0; mf < 4; ++mf) {
#pragma unroll
    for (int nf = 0; nf < 4; ++nf) {
      int col = n0 + wc * 64 + nf * 16 + lr;
      float bv = __bfloat162float(bias[col]);
#pragma unroll
      for (int r = 0; r < 4; ++r) {
        int row = m0 + wr * 64 + mf * 16 + gq * 4 + r;
        float v = acc[mf][nf][r] + bv;
        if (EPI == 1) v = fmaxf(v, 0.0f);
        if (EPI == 2) v += __bfloat162float(res[(size_t)row * N + col]);
        C[(size_t)row * N + col] = __float2bfloat16(v);
      }
    }
  }
}

// ---------------- attention: 1 block per (local) batch, wave w does heads 2w, 2w+1 ----------------
__global__ __launch_bounds__(256)
void attn_kernel(const bf16* __restrict__ qkv, const bf16* __restrict__ cw,
                 bf16* __restrict__ ctx, float* __restrict__ attn_out) {
  __shared__ __align__(16) unsigned short qkv_lds[16][1544];
  __shared__ __align__(16) unsigned short p_lds[4][16][16];
  __shared__ float att_lds[4][16][16];
  const int b = blockIdx.x;
  const int tid = threadIdx.x, lane = tid & 63, w = tid >> 6;
  const int lr = lane & 15, g = lane >> 4;
  const bf16* src = qkv + (size_t)b * 16 * 1536;
  for (int t = tid; t < 16 * 192; t += 256) {
    int row = t / 192, ch = t - row * 192;
    *reinterpret_cast<bf16x8*>(&qkv_lds[row][ch * 8]) =
        *reinterpret_cast<const bf16x8*>(src + (size_t)row * 1536 + ch * 8);
  }
  __syncthreads();
  float attacc[4] = {0.f, 0.f, 0.f, 0.f};

  for (int hh = 0; hh < 2; ++hh) {
    const int h = w * 2 + hh;
    const unsigned short* qp = &qkv_lds[lr][h * 64 + g * 8];
    const unsigned short* kp = qp + 512;
    bf16x8 q0 = *reinterpret_cast<const bf16x8*>(qp);
    bf16x8 q1 = *reinterpret_cast<const bf16x8*>(qp + 32);
    bf16x8 k0 = *reinterpret_cast<const bf16x8*>(kp);
    bf16x8 k1 = *reinterpret_cast<const bf16x8*>(kp + 32);
    f32x4 s = {0.f, 0.f, 0.f, 0.f};
    s = MFMA_BF16_16x16x32(q0, k0, s, 0, 0, 0);
    s = MFMA_BF16_16x16x32(q1, k1, s, 0, 0, 0);
    float wgt = __bfloat162float(cw[h]);
    float p[4];
#pragma unroll
    for (int r = 0; r < 4; ++r) {
      float sv = s[r] * 0.125f;
      float mx = sv;
#pragma unroll
      for (int mm = 1; mm < 16; mm <<= 1) mx = fmaxf(mx, __shfl_xor(mx, mm, 16));
      float e = expf(sv - mx);
      float sm = e;
#pragma unroll
      for (int mm = 1; mm < 16; mm <<= 1) sm += __shfl_xor(sm, mm, 16);
      p[r] = e / sm;
      attacc[r] += wgt * p[r];
    }
#pragma unroll
    for (int r = 0; r < 4; ++r) p_lds[w][g * 4 + r][lr] = (unsigned short)f2bits(p[r]);
    __syncthreads();
    bf16x8 pa;
#pragma unroll
    for (int j = 0; j < 8; ++j) pa[j] = 0;
    if (g < 2) pa = *reinterpret_cast<const bf16x8*>(&p_lds[w][lr][g * 8]);
#pragma unroll
    for (int n = 0; n < 4; ++n) {
      bf16x8 vb;
#pragma unroll
      for (int j = 0; j < 8; ++j) vb[j] = 0;
      if (g < 2) {
#pragma unroll
        for (int j = 0; j < 8; ++j)
          vb[j] = (short)qkv_lds[g * 8 + j][1024 + h * 64 + n * 16 + lr];
      }
      f32x4 z = {0.f, 0.f, 0.f, 0.f};
      f32x4 d = MFMA_BF16_16x16x32(pa, vb, z, 0, 0, 0);
#pragma unroll
      for (int r = 0; r < 4; ++r)
        ctx[(size_t)(b * 16 + g * 4 + r) * 512 + h * 64 + n * 16 + lr] = __float2bfloat16(d[r]);
    }
    __syncthreads();
  }
#pragma unroll
  for (int r = 0; r < 4; ++r) att_lds[w][g * 4 + r][lr] = attacc[r];
  __syncthreads();
  const int q = tid >> 4, kk = tid & 15;
  float ssum = att_lds[0][q][kk] + att_lds[1][q][kk] + att_lds[2][q][kk] + att_lds[3][q][kk];
  attn_out[(size_t)b * 256 + q * 16 + kk] = ssum;
}

// ---------------- LayerNorm rows of 512, one wave per row; F32OUT selects output dtype ----------------
template <int F32OUT>
__global__ __launch_bounds__(256, 4)
void ln_kernel(const bf16* in, const bf16* __restrict__ gw,
               const bf16* __restrict__ bw, void* out) {
  const int row = blockIdx.x * 4 + (threadIdx.x >> 6);
  const int lane = threadIdx.x & 63;
  const bf16* rp = in + (size_t)row * 512 + lane * 8;
  bf16x8 xv = *reinterpret_cast<const bf16x8*>(rp);
  float xf[8];
#pragma unroll
  for (int j = 0; j < 8; ++j) xf[j] = bits2f(xv[j]);
  float s = 0.f;
#pragma unroll
  for (int j = 0; j < 8; ++j) s += xf[j];
#pragma unroll
  for (int o = 32; o >= 1; o >>= 1) s += __shfl_xor(s, o, 64);
  float mu = s * (1.0f / 512.0f);
  float v = 0.f;
#pragma unroll
  for (int j = 0; j < 8; ++j) { float d = xf[j] - mu; v += d * d; }
#pragma unroll
  for (int o = 32; o >= 1; o >>= 1) v += __shfl_xor(v, o, 64);
  float rs = rsqrtf(v * (1.0f / 512.0f) + 1e-5f);
  bf16x8 gv = *reinterpret_cast<const bf16x8*>(gw + lane * 8);
  bf16x8 bv = *reinterpret_cast<const bf16x8*>(bw + lane * 8);
  if (F32OUT) {
    float* op = (float*)out + (size_t)row * 512 + lane * 8;
    f32x4 o0, o1;
#pragma unroll
    for (int j = 0; j < 4; ++j) {
      o0[j] = (xf[j] - mu) * rs * bits2f(gv[j]) + bits2f(bv[j]);
      o1[j] = (xf[4 + j] - mu) * rs * bits2f(gv[4 + j]) + bits2f(bv[4 + j]);
    }
    *reinterpret_cast<f32x4*>(op) = o0;
    *reinterpret_cast<f32x4*>(op + 4) = o1;
  } else {
    bf16x8 o8;
#pragma unroll
    for (int j = 0; j < 8; ++j)
      o8[j] = f2bits((xf[j] - mu) * rs * bits2f(gv[j]) + bits2f(bv[j]));
    *reinterpret_cast<bf16x8*>((bf16*)out + (size_t)row * 512 + lane * 8) = o8;
  }
}

extern "C" void kernel_launch(void* const* d_in, const int* in_sizes, int n_in,
                              void* d_out, int out_size, void* d_ws, size_t ws_size,
                              hipStream_t stream) {
  const void* enc  = d_in[0];
  const void* wq   = d_in[1];
  const void* bq   = d_in[2];
  const void* wk   = d_in[3];
  const void* bk   = d_in[4];
  const void* wv   = d_in[5];
  const void* bvv  = d_in[6];
  const void* wo   = d_in[7];
  const void* bo   = d_in[8];
  const void* ln1g = d_in[9];
  const void* ln1b = d_in[10];
  const void* w1   = d_in[11];
  const void* b1   = d_in[12];
  const void* w2   = d_in[13];
  const void* b2   = d_in[14];
  const void* ln2g = d_in[15];
  const void* ln2b = d_in[16];
  const void* cw   = d_in[17];

  float* outp     = (float*)d_out;                       // f32 output
  float* attn_out = outp + (size_t)33554432;             // 4096*16*512

  char* wsp = (char*)d_ws;
  size_t off = 0;
  auto alloc = [&](size_t bytes) {
    void* p = wsp + off;
    off = (off + bytes + 255) & ~(size_t)255;
    return p;
  };
  int*  flag  = (int*)alloc(4);
  float* pe   = (float*)alloc((size_t)16 * 512 * 4);
  bf16* wqkvT = (bf16*)alloc((size_t)1536 * 512 * 2);
  bf16* woT   = (bf16*)alloc((size_t)512 * 512 * 2);
  bf16* w1T   = (bf16*)alloc((size_t)2048 * 512 * 2);
  bf16* w2T   = (bf16*)alloc((size_t)512 * 2048 * 2);
  bf16* bqkv  = (bf16*)alloc((size_t)1536 * 2);
  bf16* bo_c  = (bf16*)alloc((size_t)512 * 2);
  bf16* b1_c  = (bf16*)alloc((size_t)2048 * 2);
  bf16* b2_c  = (bf16*)alloc((size_t)512 * 2);
  bf16* l1g_c = (bf16*)alloc((size_t)512 * 2);
  bf16* l1b_c = (bf16*)alloc((size_t)512 * 2);
  bf16* l2g_c = (bf16*)alloc((size_t)512 * 2);
  bf16* l2b_c = (bf16*)alloc((size_t)512 * 2);
  bf16* cw_c  = (bf16*)alloc((size_t)8 * 2);
  size_t fixed_bytes = off;

  int CH = 1024;
  {
    const int cands[6] = {65536, 32768, 16384, 8192, 4096, 2048};
    for (int ci = 0; ci < 6; ++ci) {
      size_t need = fixed_bytes + (size_t)cands[ci] * 6144 + (1u << 20);
      if (need <= ws_size) { CH = cands[ci]; break; }
    }
  }
  bf16* x_c   = (bf16*)alloc((size_t)CH * 512 * 2);
  bf16* ctx_c = (bf16*)alloc((size_t)CH * 512 * 2);   // doubles as y after O-proj
  bf16* share = (bf16*)alloc((size_t)CH * 2048 * 2);  // qkv (CH*1536) then h (CH*2048)
  bf16* qkv = share;
  bf16* h   = share;
  bf16* y_c = ctx_c;

  detect_kernel<<<1, 256, 0, stream>>>((const unsigned short*)wq, flag);
  pe_kernel<<<16, 256, 0, stream>>>(pe);
  {
    TArgs ta;
    ta.seg[0] = {wq, (unsigned short*)wqkvT,               512,  512,    0};
    ta.seg[1] = {wk, (unsigned short*)(wqkvT + 512 * 512), 512,  512,  256};
    ta.seg[2] = {wv, (unsigned short*)(wqkvT + 1024 * 512),512,  512,  512};
    ta.seg[3] = {wo, (unsigned short*)woT,                 512,  512,  768};
    ta.seg[4] = {w1, (unsigned short*)w1T,                 512, 2048, 1024};
    ta.seg[5] = {w2, (unsigned short*)w2T,                2048,  512, 2048};
    ta.nseg = 6;
    transpose_all_kernel<<<3072, 256, 0, stream>>>(ta, flag);
  }
  {
    SmallCvtArgs a;
    a.seg[0]  = {bq,   bqkv,        512};
    a.seg[1]  = {bk,   bqkv + 512,  512};
    a.seg[2]  = {bvv,  bqkv + 1024, 512};
    a.seg[3]  = {bo,   bo_c,        512};
    a.seg[4]  = {b1,   b1_c,       2048};
    a.seg[5]  = {b2,   b2_c,        512};
    a.seg[6]  = {ln1g, l1g_c,       512};
    a.seg[7]  = {ln1b, l1b_c,       512};
    a.seg[8]  = {ln2g, l2g_c,       512};
    a.seg[9]  = {ln2b, l2b_c,       512};
    a.seg[10] = {cw,   cw_c,          8};
    small_cvt_kernel<<<11, 256, 0, stream>>>(a, flag);
  }

  for (int r0 = 0; r0 < 65536; r0 += CH) {
    float* out_c = outp + (size_t)r0 * 512;
    float* ao_c  = attn_out + (size_t)(r0 / 16) * 256;
    add_pe2_kernel<<<CH / 4, 256, 0, stream>>>(
        (const void*)((const bf16*)enc + (size_t)r0 * 512),
        (const void*)((const float*)enc + (size_t)r0 * 512), pe, x_c, flag);
    // QKV projection: [CH,512] @ [512,1536]
    gemm20_kernel<0><<<(CH / 256) * 6, 1024, 0, stream>>>(x_c, wqkvT, bqkv, nullptr, qkv, CH, 1536, 512);
    // attention + conv_att (attn_out in f32)
    attn_kernel<<<CH / 16, 256, 0, stream>>>(qkv, cw_c, ctx_c, ao_c);
    // O-proj + bias + residual(x), in-place over x -> preLN1
    gemm20_kernel<2><<<(CH / 256) * 2, 1024, 0, stream>>>(ctx_c, woT, bo_c, x_c, x_c, CH, 512, 512);
    // LN1: x -> y (bf16, reuses ctx buffer)
    ln_kernel<0><<<CH / 4, 256, 0, stream>>>(x_c, l1g_c, l1b_c, y_c);
    // FFN1 + relu
    gemm20_kernel<1><<<(CH / 256) * 8, 1024, 0, stream>>>(y_c, w1T, b1_c, nullptr, h, CH, 2048, 512);
    // FFN2 + bias + residual(y), in-place over y -> preLN2
    gemm20_kernel<2><<<(CH / 256) * 2, 1024, 0, stream>>>(h, w2T, b2_c, y_c, y_c, CH, 512, 2048);
    // LN2 -> f32 d_out rows
    ln_kernel<1><<<CH / 4, 256, 0, stream>>>(y_c, l2g_c, l2b_c, out_c);
  }
}

// Round 21
// 779.355 us; speedup vs baseline: 1.0061x; 1.0061x over previous
//
#include <hip/hip_runtime.h>
#include <hip/hip_bf16.h>

using bf16 = __hip_bfloat16;
typedef __attribute__((ext_vector_type(8))) short bf16x8;
typedef __attribute__((ext_vector_type(4))) float f32x4;

#define MFMA_BF16_16x16x32 __builtin_amdgcn_mfma_f32_16x16x32_bf16

__device__ __forceinline__ float bits2f(short b) {
  unsigned u = ((unsigned)(unsigned short)b) << 16;
  return __uint_as_float(u);
}
__device__ __forceinline__ short f2bits(float f) {
  bf16 h = __float2bfloat16(f);
  return *reinterpret_cast<short*>(&h);
}

// bijective XCD swizzle for nwg % 8 == 0
__device__ __forceinline__ int xcd_swz(int bid, int nwg) {
  int q = nwg >> 3;
  return (bid & 7) * q + (bid >> 3);
}

// LDS bank swizzle (involution: source bits 9:7, target bits 6:4 -- disjoint).
// Measured 0 bank conflicts on this 64B-row geometry (r7-r20 counters).
__device__ __forceinline__ int bank_swz(int off) {
  return off ^ (((off >> 7) & 7) << 4);
}

// ---------------- input-dtype detection (flag=1 -> inputs are f32) ----------------
__global__ void detect_kernel(const unsigned short* __restrict__ w, int* __restrict__ flag) {
  __shared__ int bad;
  if (threadIdx.x == 0) bad = 0;
  __syncthreads();
  float m = 0.f;
#pragma unroll
  for (int j = 0; j < 4; ++j)
    m = fmaxf(m, fabsf(bits2f((short)w[threadIdx.x * 4 + j])));
  if (m > 4.0f) atomicOr(&bad, 1);
  __syncthreads();
  if (threadIdx.x == 0) *flag = bad ? 1 : 0;
}

// ---------------- positional encoding table (16 x 512, f32) ----------------
__global__ void pe_kernel(float* __restrict__ pe) {
  int s = blockIdx.x;
  int i = threadIdx.x;
  float dv = expf((float)(2 * i) * (-9.210340371976184f / 512.0f)); // -ln(10000)/512
  float ang = (float)s * dv;
  pe[s * 512 + 2 * i]     = sinf(ang);
  pe[s * 512 + 2 * i + 1] = cosf(ang);
}

// ---------------- x = enc + pe; enc base passed in both dtype interpretations ----------------
__global__ __launch_bounds__(256) void add_pe2_kernel(const void* __restrict__ enc_bf,
                                                      const void* __restrict__ enc_f32,
                                                      const float* __restrict__ pe,
                                                      bf16* __restrict__ x,
                                                      const int* __restrict__ flag) {
  size_t i = ((size_t)blockIdx.x * 256 + threadIdx.x) * 8;
  int col  = (int)(i & 511);
  int srow = (int)((i >> 9) & 15);
  float e[8];
  if (*flag) {
    const float* ef = (const float*)enc_f32 + i;
    f32x4 a = *reinterpret_cast<const f32x4*>(ef);
    f32x4 b = *reinterpret_cast<const f32x4*>(ef + 4);
#pragma unroll
    for (int j = 0; j < 4; ++j) { e[j] = a[j]; e[4 + j] = b[j]; }
  } else {
    bf16x8 ev = *reinterpret_cast<const bf16x8*>((const bf16*)enc_bf + i);
#pragma unroll
    for (int j = 0; j < 8; ++j) e[j] = bits2f(ev[j]);
  }
  const float* pp = pe + srow * 512 + col;
  f32x4 p0 = *reinterpret_cast<const f32x4*>(pp);
  f32x4 p1 = *reinterpret_cast<const f32x4*>(pp + 4);
  bf16x8 o;
#pragma unroll
  for (int j = 0; j < 4; ++j) o[j] = f2bits(e[j] + p0[j]);
#pragma unroll
  for (int j = 0; j < 4; ++j) o[4 + j] = f2bits(e[4 + j] + p1[j]);
  *reinterpret_cast<bf16x8*>(x + i) = o;
}

// ---------------- batched transpose + cvt: 6 weight matrices in ONE launch ----------------
struct TSeg { const void* src; unsigned short* dst; int R, C, base; };
struct TArgs { TSeg seg[6]; int nseg; };
__global__ __launch_bounds__(256) void transpose_all_kernel(TArgs a, const int* __restrict__ flag) {
  __shared__ unsigned short t[32][33];
  int bid = blockIdx.x;
  TSeg s = a.seg[0];
#pragma unroll
  for (int k = 1; k < 6; ++k)
    if (bid >= a.seg[k].base) s = a.seg[k];
  int local = bid - s.base;
  int nbx = s.C >> 5;
  int bx = (local % nbx) * 32;
  int by = (local / nbx) * 32;
  int lx = threadIdx.x & 31, ly = threadIdx.x >> 5;
  if (*flag) {
    const float* sp = (const float*)s.src;
#pragma unroll
    for (int i = 0; i < 4; ++i)
      t[ly + i * 8][lx] = (unsigned short)f2bits(sp[(size_t)(by + ly + i * 8) * s.C + bx + lx]);
  } else {
    const unsigned short* sp = (const unsigned short*)s.src;
#pragma unroll
    for (int i = 0; i < 4; ++i)
      t[ly + i * 8][lx] = sp[(size_t)(by + ly + i * 8) * s.C + bx + lx];
  }
  __syncthreads();
#pragma unroll
  for (int i = 0; i < 4; ++i)
    s.dst[(size_t)(bx + ly + i * 8) * s.R + by + lx] = t[lx][ly + i * 8];
}

// ---------------- batched small-vector convert ----------------
struct SmallSeg { const void* src; bf16* dst; int n; };
struct SmallCvtArgs { SmallSeg seg[11]; };
__global__ __launch_bounds__(256) void small_cvt_kernel(SmallCvtArgs a, const int* __restrict__ flag) {
  SmallSeg s = a.seg[blockIdx.x];
  int f = *flag;
  for (int i = threadIdx.x; i < s.n; i += 256) {
    float v = f ? ((const float*)s.src)[i] : bits2f(((const short*)s.src)[i]);
    s.dst[i] = __float2bfloat16(v);
  }
}

// ---------------- 256x256 GEMM, BK=32, 1024 thr, 4-buf LDS, prefetch depth 3 ----------------
// C[M,N] = A[M,K] @ Bt[N,K]^T + bias; EPI: 0=bias, 1=bias+relu, 2=bias+residual.
// 1024 thr = 16 waves (4M x 4N), per-wave 64x64 (acc 64). LDS 4 x 32 KB = 128 KiB ->
// 1 block/CU, 16 waves. r19 structure (1 barrier/step, COUNTED vmcnt -- r20 proved the
// counted wait is worth more than halved barriers) with prefetch distance 3:
// Step t: {reads(t) buf t&3; stage(t+3) -> buf (t+3)&3 (2 loads/thread); 16 MFMA;
//          lgkm(0); vmcnt(4) (leaves tiles t+2,t+3 in flight, FORCES t+1 landed);
//          one barrier}. Each load now has ~2 MFMA-steps (~2500cyc) to cover HBM.
// Hazard: stage(t+3) overwrites buf (t-1)&3, whose reads completed before the
// step-(t-1) barrier (consumed by MFMAs; lgkm(0) precedes it). Race-free.
template <int EPI>
__global__ __launch_bounds__(1024, 4)
void gemm21_kernel(const bf16* __restrict__ A, const bf16* __restrict__ Bt,
                   const bf16* __restrict__ bias, const bf16* res,
                   bf16* C, int M, int N, int K) {
  __shared__ __align__(16) char lds[4][32768];   // per buf: A 16K + B 16K; 128 KiB
  const int nbn = N >> 8;
  const int wg = xcd_swz(blockIdx.x, gridDim.x);
  const int bn = wg % nbn, bm = wg / nbn;
  const int m0 = bm << 8, n0 = bn << 8;
  const int tid = threadIdx.x, lane = tid & 63, wid = tid >> 6;
  const int wr = wid >> 2, wc = wid & 3;
  const int lr = lane & 15, gq = lane >> 4;
  const int nt = K >> 5;                          // 16 (K=512) or 64 (K=2048)

  f32x4 acc[4][4] = {};
  bf16x8 a[4], b[4];

  auto stage = [&](int s, int buf) {
    {                                             // A tile: 16 KB, 1 load/thread
      int p = tid * 16;
      int q = bank_swz(p);
      const bf16* src = A + (size_t)(m0 + (q >> 6)) * K + s * 32 + ((q & 63) >> 1);
      __builtin_amdgcn_global_load_lds(
          (const __attribute__((address_space(1))) void*)src,
          (__attribute__((address_space(3))) void*)&lds[buf][wid * 1024], 16, 0, 0);
    }
    {                                             // B tile: 16 KB, 1 load/thread
      int p = tid * 16;
      int q = bank_swz(p);
      const bf16* src = Bt + (size_t)(n0 + (q >> 6)) * K + s * 32 + ((q & 63) >> 1);
      __builtin_amdgcn_global_load_lds(
          (const __attribute__((address_space(1))) void*)src,
          (__attribute__((address_space(3))) void*)&lds[buf][16384 + wid * 1024], 16, 0, 0);
    }
  };

  auto rdA = [&](int buf, int row) -> bf16x8 {
    int off = bank_swz(row * 64 + gq * 16);
    return *reinterpret_cast<const bf16x8*>(&lds[buf][off]);
  };
  auto rdB = [&](int buf, int row) -> bf16x8 {
    int off = bank_swz(row * 64 + gq * 16);
    return *reinterpret_cast<const bf16x8*>(&lds[buf][16384 + off]);
  };

  // prologue: tiles 0,1,2 into bufs 0,1,2 (6 loads/thread).
  // vmcnt(4): tile0's 2 loads landed; tiles 1,2 may stay in flight.
  stage(0, 0); stage(1, 1); stage(2, 2);
  asm volatile("s_waitcnt vmcnt(4)" ::: "memory");
  __builtin_amdgcn_s_barrier();

  for (int t = 0; t < nt; ++t) {
    const int bufr = t & 3;
#pragma unroll
    for (int mf = 0; mf < 4; ++mf) a[mf] = rdA(bufr, wr * 64 + mf * 16 + lr);
#pragma unroll
    for (int nf = 0; nf < 4; ++nf) b[nf] = rdB(bufr, wc * 64 + nf * 16 + lr);
    const bool st = (t + 3 < nt);
    if (st) stage(t + 3, (t + 3) & 3);            // writes buf (t-1)&3: reads(t-1) done
    __builtin_amdgcn_s_setprio(1);
#pragma unroll
    for (int mf = 0; mf < 4; ++mf)
#pragma unroll
      for (int nf = 0; nf < 4; ++nf)
        acc[mf][nf] = MFMA_BF16_16x16x32(a[mf], b[nf], acc[mf][nf], 0, 0, 0);
    __builtin_amdgcn_s_setprio(0);
    asm volatile("s_waitcnt lgkmcnt(0)" ::: "memory");   // reads consumed; fences DS
    if (st) asm volatile("s_waitcnt vmcnt(4)" ::: "memory");  // t+1 landed (counted)
    else    asm volatile("s_waitcnt vmcnt(0)" ::: "memory");  // tail drain
    __builtin_amdgcn_s_barrier();                 // single barrier per step
  }

  // epilogue: per-wave 64x64
#pragma unroll
  for (int mf = 0; mf < 4; ++mf) {
#pragma unroll
    for (int nf = 0; nf < 4; ++nf) {
      int col = n0 + wc * 64 + nf * 16 + lr;
      float bv = __bfloat162float(bias[col]);
#pragma unroll
      for (int r = 0; r < 4; ++r) {
        int row = m0 + wr * 64 + mf * 16 + gq * 4 + r;
        float v = acc[mf][nf][r] + bv;
        if (EPI == 1) v = fmaxf(v, 0.0f);
        if (EPI == 2) v += __bfloat162float(res[(size_t)row * N + col]);
        C[(size_t)row * N + col] = __float2bfloat16(v);
      }
    }
  }
}

// ---------------- attention: 1 block per (local) batch, wave w does heads 2w, 2w+1 ----------------
__global__ __launch_bounds__(256)
void attn_kernel(const bf16* __restrict__ qkv, const bf16* __restrict__ cw,
                 bf16* __restrict__ ctx, float* __restrict__ attn_out) {
  __shared__ __align__(16) unsigned short qkv_lds[16][1544];
  __shared__ __align__(16) unsigned short p_lds[4][16][16];
  __shared__ float att_lds[4][16][16];
  const int b = blockIdx.x;
  const int tid = threadIdx.x, lane = tid & 63, w = tid >> 6;
  const int lr = lane & 15, g = lane >> 4;
  const bf16* src = qkv + (size_t)b * 16 * 1536;
  for (int t = tid; t < 16 * 192; t += 256) {
    int row = t / 192, ch = t - row * 192;
    *reinterpret_cast<bf16x8*>(&qkv_lds[row][ch * 8]) =
        *reinterpret_cast<const bf16x8*>(src + (size_t)row * 1536 + ch * 8);
  }
  __syncthreads();
  float attacc[4] = {0.f, 0.f, 0.f, 0.f};

  for (int hh = 0; hh < 2; ++hh) {
    const int h = w * 2 + hh;
    const unsigned short* qp = &qkv_lds[lr][h * 64 + g * 8];
    const unsigned short* kp = qp + 512;
    bf16x8 q0 = *reinterpret_cast<const bf16x8*>(qp);
    bf16x8 q1 = *reinterpret_cast<const bf16x8*>(qp + 32);
    bf16x8 k0 = *reinterpret_cast<const bf16x8*>(kp);
    bf16x8 k1 = *reinterpret_cast<const bf16x8*>(kp + 32);
    f32x4 s = {0.f, 0.f, 0.f, 0.f};
    s = MFMA_BF16_16x16x32(q0, k0, s, 0, 0, 0);
    s = MFMA_BF16_16x16x32(q1, k1, s, 0, 0, 0);
    float wgt = __bfloat162float(cw[h]);
    float p[4];
#pragma unroll
    for (int r = 0; r < 4; ++r) {
      float sv = s[r] * 0.125f;
      float mx = sv;
#pragma unroll
      for (int mm = 1; mm < 16; mm <<= 1) mx = fmaxf(mx, __shfl_xor(mx, mm, 16));
      float e = expf(sv - mx);
      float sm = e;
#pragma unroll
      for (int mm = 1; mm < 16; mm <<= 1) sm += __shfl_xor(sm, mm, 16);
      p[r] = e / sm;
      attacc[r] += wgt * p[r];
    }
#pragma unroll
    for (int r = 0; r < 4; ++r) p_lds[w][g * 4 + r][lr] = (unsigned short)f2bits(p[r]);
    __syncthreads();
    bf16x8 pa;
#pragma unroll
    for (int j = 0; j < 8; ++j) pa[j] = 0;
    if (g < 2) pa = *reinterpret_cast<const bf16x8*>(&p_lds[w][lr][g * 8]);
#pragma unroll
    for (int n = 0; n < 4; ++n) {
      bf16x8 vb;
#pragma unroll
      for (int j = 0; j < 8; ++j) vb[j] = 0;
      if (g < 2) {
#pragma unroll
        for (int j = 0; j < 8; ++j)
          vb[j] = (short)qkv_lds[g * 8 + j][1024 + h * 64 + n * 16 + lr];
      }
      f32x4 z = {0.f, 0.f, 0.f, 0.f};
      f32x4 d = MFMA_BF16_16x16x32(pa, vb, z, 0, 0, 0);
#pragma unroll
      for (int r = 0; r < 4; ++r)
        ctx[(size_t)(b * 16 + g * 4 + r) * 512 + h * 64 + n * 16 + lr] = __float2bfloat16(d[r]);
    }
    __syncthreads();
  }
#pragma unroll
  for (int r = 0; r < 4; ++r) att_lds[w][g * 4 + r][lr] = attacc[r];
  __syncthreads();
  const int q = tid >> 4, kk = tid & 15;
  float ssum = att_lds[0][q][kk] + att_lds[1][q][kk] + att_lds[2][q][kk] + att_lds[3][q][kk];
  attn_out[(size_t)b * 256 + q * 16 + kk] = ssum;
}

// ---------------- LayerNorm rows of 512, one wave per row; F32OUT selects output dtype ----------------
template <int F32OUT>
__global__ __launch_bounds__(256, 4)
void ln_kernel(const bf16* in, const bf16* __restrict__ gw,
               const bf16* __restrict__ bw, void* out) {
  const int row = blockIdx.x * 4 + (threadIdx.x >> 6);
  const int lane = threadIdx.x & 63;
  const bf16* rp = in + (size_t)row * 512 + lane * 8;
  bf16x8 xv = *reinterpret_cast<const bf16x8*>(rp);
  float xf[8];
#pragma unroll
  for (int j = 0; j < 8; ++j) xf[j] = bits2f(xv[j]);
  float s = 0.f;
#pragma unroll
  for (int j = 0; j < 8; ++j) s += xf[j];
#pragma unroll
  for (int o = 32; o >= 1; o >>= 1) s += __shfl_xor(s, o, 64);
  float mu = s * (1.0f / 512.0f);
  float v = 0.f;
#pragma unroll
  for (int j = 0; j < 8; ++j) { float d = xf[j] - mu; v += d * d; }
#pragma unroll
  for (int o = 32; o >= 1; o >>= 1) v += __shfl_xor(v, o, 64);
  float rs = rsqrtf(v * (1.0f / 512.0f) + 1e-5f);
  bf16x8 gv = *reinterpret_cast<const bf16x8*>(gw + lane * 8);
  bf16x8 bv = *reinterpret_cast<const bf16x8*>(bw + lane * 8);
  if (F32OUT) {
    float* op = (float*)out + (size_t)row * 512 + lane * 8;
    f32x4 o0, o1;
#pragma unroll
    for (int j = 0; j < 4; ++j) {
      o0[j] = (xf[j] - mu) * rs * bits2f(gv[j]) + bits2f(bv[j]);
      o1[j] = (xf[4 + j] - mu) * rs * bits2f(gv[4 + j]) + bits2f(bv[4 + j]);
    }
    *reinterpret_cast<f32x4*>(op) = o0;
    *reinterpret_cast<f32x4*>(op + 4) = o1;
  } else {
    bf16x8 o8;
#pragma unroll
    for (int j = 0; j < 8; ++j)
      o8[j] = f2bits((xf[j] - mu) * rs * bits2f(gv[j]) + bits2f(bv[j]));
    *reinterpret_cast<bf16x8*>((bf16*)out + (size_t)row * 512 + lane * 8) = o8;
  }
}

extern "C" void kernel_launch(void* const* d_in, const int* in_sizes, int n_in,
                              void* d_out, int out_size, void* d_ws, size_t ws_size,
                              hipStream_t stream) {
  const void* enc  = d_in[0];
  const void* wq   = d_in[1];
  const void* bq   = d_in[2];
  const void* wk   = d_in[3];
  const void* bk   = d_in[4];
  const void* wv   = d_in[5];
  const void* bvv  = d_in[6];
  const void* wo   = d_in[7];
  const void* bo   = d_in[8];
  const void* ln1g = d_in[9];
  const void* ln1b = d_in[10];
  const void* w1   = d_in[11];
  const void* b1   = d_in[12];
  const void* w2   = d_in[13];
  const void* b2   = d_in[14];
  const void* ln2g = d_in[15];
  const void* ln2b = d_in[16];
  const void* cw   = d_in[17];

  float* outp     = (float*)d_out;                       // f32 output
  float* attn_out = outp + (size_t)33554432;             // 4096*16*512

  char* wsp = (char*)d_ws;
  size_t off = 0;
  auto alloc = [&](size_t bytes) {
    void* p = wsp + off;
    off = (off + bytes + 255) & ~(size_t)255;
    return p;
  };
  int*  flag  = (int*)alloc(4);
  float* pe   = (float*)alloc((size_t)16 * 512 * 4);
  bf16* wqkvT = (bf16*)alloc((size_t)1536 * 512 * 2);
  bf16* woT   = (bf16*)alloc((size_t)512 * 512 * 2);
  bf16* w1T   = (bf16*)alloc((size_t)2048 * 512 * 2);
  bf16* w2T   = (bf16*)alloc((size_t)512 * 2048 * 2);
  bf16* bqkv  = (bf16*)alloc((size_t)1536 * 2);
  bf16* bo_c  = (bf16*)alloc((size_t)512 * 2);
  bf16* b1_c  = (bf16*)alloc((size_t)2048 * 2);
  bf16* b2_c  = (bf16*)alloc((size_t)512 * 2);
  bf16* l1g_c = (bf16*)alloc((size_t)512 * 2);
  bf16* l1b_c = (bf16*)alloc((size_t)512 * 2);
  bf16* l2g_c = (bf16*)alloc((size_t)512 * 2);
  bf16* l2b_c = (bf16*)alloc((size_t)512 * 2);
  bf16* cw_c  = (bf16*)alloc((size_t)8 * 2);
  size_t fixed_bytes = off;

  int CH = 1024;
  {
    const int cands[6] = {65536, 32768, 16384, 8192, 4096, 2048};
    for (int ci = 0; ci < 6; ++ci) {
      size_t need = fixed_bytes + (size_t)cands[ci] * 6144 + (1u << 20);
      if (need <= ws_size) { CH = cands[ci]; break; }
    }
  }
  bf16* x_c   = (bf16*)alloc((size_t)CH * 512 * 2);
  bf16* ctx_c = (bf16*)alloc((size_t)CH * 512 * 2);   // doubles as y after O-proj
  bf16* share = (bf16*)alloc((size_t)CH * 2048 * 2);  // qkv (CH*1536) then h (CH*2048)
  bf16* qkv = share;
  bf16* h   = share;
  bf16* y_c = ctx_c;

  detect_kernel<<<1, 256, 0, stream>>>((const unsigned short*)wq, flag);
  pe_kernel<<<16, 256, 0, stream>>>(pe);
  {
    TArgs ta;
    ta.seg[0] = {wq, (unsigned short*)wqkvT,               512,  512,    0};
    ta.seg[1] = {wk, (unsigned short*)(wqkvT + 512 * 512), 512,  512,  256};
    ta.seg[2] = {wv, (unsigned short*)(wqkvT + 1024 * 512),512,  512,  512};
    ta.seg[3] = {wo, (unsigned short*)woT,                 512,  512,  768};
    ta.seg[4] = {w1, (unsigned short*)w1T,                 512, 2048, 1024};
    ta.seg[5] = {w2, (unsigned short*)w2T,                2048,  512, 2048};
    ta.nseg = 6;
    transpose_all_kernel<<<3072, 256, 0, stream>>>(ta, flag);
  }
  {
    SmallCvtArgs a;
    a.seg[0]  = {bq,   bqkv,        512};
    a.seg[1]  = {bk,   bqkv + 512,  512};
    a.seg[2]  = {bvv,  bqkv + 1024, 512};
    a.seg[3]  = {bo,   bo_c,        512};
    a.seg[4]  = {b1,   b1_c,       2048};
    a.seg[5]  = {b2,   b2_c,        512};
    a.seg[6]  = {ln1g, l1g_c,       512};
    a.seg[7]  = {ln1b, l1b_c,       512};
    a.seg[8]  = {ln2g, l2g_c,       512};
    a.seg[9]  = {ln2b, l2b_c,       512};
    a.seg[10] = {cw,   cw_c,          8};
    small_cvt_kernel<<<11, 256, 0, stream>>>(a, flag);
  }

  for (int r0 = 0; r0 < 65536; r0 += CH) {
    float* out_c = outp + (size_t)r0 * 512;
    float* ao_c  = attn_out + (size_t)(r0 / 16) * 256;
    add_pe2_kernel<<<CH / 4, 256, 0, stream>>>(
        (const void*)((const bf16*)enc + (size_t)r0 * 512),
        (const void*)((const float*)enc + (size_t)r0 * 512), pe, x_c, flag);
    // QKV projection: [CH,512] @ [512,1536]
    gemm21_kernel<0><<<(CH / 256) * 6, 1024, 0, stream>>>(x_c, wqkvT, bqkv, nullptr, qkv, CH, 1536, 512);
    // attention + conv_att (attn_out in f32)
    attn_kernel<<<CH / 16, 256, 0, stream>>>(qkv, cw_c, ctx_c, ao_c);
    // O-proj + bias + residual(x), in-place over x -> preLN1
    gemm21_kernel<2><<<(CH / 256) * 2, 1024, 0, stream>>>(ctx_c, woT, bo_c, x_c, x_c, CH, 512, 512);
    // LN1: x -> y (bf16, reuses ctx buffer)
    ln_kernel<0><<<CH / 4, 256, 0, stream>>>(x_c, l1g_c, l1b_c, y_c);
    // FFN1 + relu
    gemm21_kernel<1><<<(CH / 256) * 8, 1024, 0, stream>>>(y_c, w1T, b1_c, nullptr, h, CH, 2048, 512);
    // FFN2 + bias + residual(y), in-place over y -> preLN2
    gemm21_kernel<2><<<(CH / 256) * 2, 1024, 0, stream>>>(h, w2T, b2_c, y_c, y_c, CH, 512, 2048);
    // LN2 -> f32 d_out rows
    ln_kernel<1><<<CH / 4, 256, 0, stream>>>(y_c, l2g_c, l2b_c, out_c);
  }
}

// Round 22
// 772.321 us; speedup vs baseline: 1.0152x; 1.0091x over previous
//
#include <hip/hip_runtime.h>
#include <hip/hip_bf16.h>

using bf16 = __hip_bfloat16;
typedef __attribute__((ext_vector_type(8))) short bf16x8;
typedef __attribute__((ext_vector_type(4))) float f32x4;

#define MFMA_BF16_16x16x32 __builtin_amdgcn_mfma_f32_16x16x32_bf16

__device__ __forceinline__ float bits2f(short b) {
  unsigned u = ((unsigned)(unsigned short)b) << 16;
  return __uint_as_float(u);
}
__device__ __forceinline__ short f2bits(float f) {
  bf16 h = __float2bfloat16(f);
  return *reinterpret_cast<short*>(&h);
}

// bijective XCD swizzle for nwg % 8 == 0
__device__ __forceinline__ int xcd_swz(int bid, int nwg) {
  int q = nwg >> 3;
  return (bid & 7) * q + (bid >> 3);
}

// LDS bank swizzle (involution: source bits 9:7, target bits 6:4 -- disjoint).
// Measured 0 bank conflicts on this 64B-row geometry (r7-r21 counters).
__device__ __forceinline__ int bank_swz(int off) {
  return off ^ (((off >> 7) & 7) << 4);
}

// ---------------- input-dtype detection (flag=1 -> inputs are f32) ----------------
__global__ void detect_kernel(const unsigned short* __restrict__ w, int* __restrict__ flag) {
  __shared__ int bad;
  if (threadIdx.x == 0) bad = 0;
  __syncthreads();
  float m = 0.f;
#pragma unroll
  for (int j = 0; j < 4; ++j)
    m = fmaxf(m, fabsf(bits2f((short)w[threadIdx.x * 4 + j])));
  if (m > 4.0f) atomicOr(&bad, 1);
  __syncthreads();
  if (threadIdx.x == 0) *flag = bad ? 1 : 0;
}

// ---------------- positional encoding table (16 x 512, f32) ----------------
__global__ void pe_kernel(float* __restrict__ pe) {
  int s = blockIdx.x;
  int i = threadIdx.x;
  float dv = expf((float)(2 * i) * (-9.210340371976184f / 512.0f)); // -ln(10000)/512
  float ang = (float)s * dv;
  pe[s * 512 + 2 * i]     = sinf(ang);
  pe[s * 512 + 2 * i + 1] = cosf(ang);
}

// ---------------- x = enc + pe; enc base passed in both dtype interpretations ----------------
__global__ __launch_bounds__(256) void add_pe2_kernel(const void* __restrict__ enc_bf,
                                                      const void* __restrict__ enc_f32,
                                                      const float* __restrict__ pe,
                                                      bf16* __restrict__ x,
                                                      const int* __restrict__ flag) {
  size_t i = ((size_t)blockIdx.x * 256 + threadIdx.x) * 8;
  int col  = (int)(i & 511);
  int srow = (int)((i >> 9) & 15);
  float e[8];
  if (*flag) {
    const float* ef = (const float*)enc_f32 + i;
    f32x4 a = *reinterpret_cast<const f32x4*>(ef);
    f32x4 b = *reinterpret_cast<const f32x4*>(ef + 4);
#pragma unroll
    for (int j = 0; j < 4; ++j) { e[j] = a[j]; e[4 + j] = b[j]; }
  } else {
    bf16x8 ev = *reinterpret_cast<const bf16x8*>((const bf16*)enc_bf + i);
#pragma unroll
    for (int j = 0; j < 8; ++j) e[j] = bits2f(ev[j]);
  }
  const float* pp = pe + srow * 512 + col;
  f32x4 p0 = *reinterpret_cast<const f32x4*>(pp);
  f32x4 p1 = *reinterpret_cast<const f32x4*>(pp + 4);
  bf16x8 o;
#pragma unroll
  for (int j = 0; j < 4; ++j) o[j] = f2bits(e[j] + p0[j]);
#pragma unroll
  for (int j = 0; j < 4; ++j) o[4 + j] = f2bits(e[4 + j] + p1[j]);
  *reinterpret_cast<bf16x8*>(x + i) = o;
}

// ---------------- batched transpose + cvt: 6 weight matrices in ONE launch ----------------
struct TSeg { const void* src; unsigned short* dst; int R, C, base; };
struct TArgs { TSeg seg[6]; int nseg; };
__global__ __launch_bounds__(256) void transpose_all_kernel(TArgs a, const int* __restrict__ flag) {
  __shared__ unsigned short t[32][33];
  int bid = blockIdx.x;
  TSeg s = a.seg[0];
#pragma unroll
  for (int k = 1; k < 6; ++k)
    if (bid >= a.seg[k].base) s = a.seg[k];
  int local = bid - s.base;
  int nbx = s.C >> 5;
  int bx = (local % nbx) * 32;
  int by = (local / nbx) * 32;
  int lx = threadIdx.x & 31, ly = threadIdx.x >> 5;
  if (*flag) {
    const float* sp = (const float*)s.src;
#pragma unroll
    for (int i = 0; i < 4; ++i)
      t[ly + i * 8][lx] = (unsigned short)f2bits(sp[(size_t)(by + ly + i * 8) * s.C + bx + lx]);
  } else {
    const unsigned short* sp = (const unsigned short*)s.src;
#pragma unroll
    for (int i = 0; i < 4; ++i)
      t[ly + i * 8][lx] = sp[(size_t)(by + ly + i * 8) * s.C + bx + lx];
  }
  __syncthreads();
#pragma unroll
  for (int i = 0; i < 4; ++i)
    s.dst[(size_t)(bx + ly + i * 8) * s.R + by + lx] = t[lx][ly + i * 8];
}

// ---------------- batched small-vector convert ----------------
struct SmallSeg { const void* src; bf16* dst; int n; };
struct SmallCvtArgs { SmallSeg seg[11]; };
__global__ __launch_bounds__(256) void small_cvt_kernel(SmallCvtArgs a, const int* __restrict__ flag) {
  SmallSeg s = a.seg[blockIdx.x];
  int f = *flag;
  for (int i = threadIdx.x; i < s.n; i += 256) {
    float v = f ? ((const float*)s.src)[i] : bits2f(((const short*)s.src)[i]);
    s.dst[i] = __float2bfloat16(v);
  }
}

// ---------------- 256x256 GEMM, BK=32, 1024 thr, TRIPLE-buffered LDS ----------------
// C[M,N] = A[M,K] @ Bt[N,K]^T + bias; EPI: 0=bias, 1=bias+relu, 2=bias+residual.
// SESSION-BEST configuration (r19: 774.5 us total, FFN2 ~188 us, MfmaUtil 31%,
// 0 bank conflicts). 1024 thr = 16 waves (4M x 4N), per-wave 64x64 (acc 64).
// LDS: per buf A 16K + B 16K = 32K, x3 = 96 KiB -> 1 block/CU, 16 waves/CU, with
// SHARED A/B tiles (vs 2x 256x128 blocks: stage-writes 48->32 KB/step/CU, one
// barrier domain instead of two).
// Step t: {reads(t) buf t%3; stage(t+2) buf (t+2)%3 (2 loads/thread); 16 MFMA/wave;
//          lgkm(0); counted vmcnt(2) (forces tile t+1 landed, leaves t+2 in flight);
//          one barrier}. Hazard: stage(t+2) overwrites buf (t-1)%3, whose reads all
// completed before the step-(t-1) barrier (consumed by MFMAs; lgkm(0) precedes it).
template <int EPI>
__global__ __launch_bounds__(1024, 4)
void gemm19_kernel(const bf16* __restrict__ A, const bf16* __restrict__ Bt,
                   const bf16* __restrict__ bias, const bf16* res,
                   bf16* C, int M, int N, int K) {
  __shared__ __align__(16) char lds[3][32768];   // per buf: A 16K + B 16K; 96 KiB
  const int nbn = N >> 8;
  const int wg = xcd_swz(blockIdx.x, gridDim.x);
  const int bn = wg % nbn, bm = wg / nbn;
  const int m0 = bm << 8, n0 = bn << 8;
  const int tid = threadIdx.x, lane = tid & 63, wid = tid >> 6;
  const int wr = wid >> 2, wc = wid & 3;
  const int lr = lane & 15, gq = lane >> 4;
  const int nt = K >> 5;

  f32x4 acc[4][4] = {};
  bf16x8 a[4], b[4];

  auto stage = [&](int s, int buf) {
    {                                             // A tile: 16 KB, 1 load/thread
      int p = tid * 16;
      int q = bank_swz(p);
      const bf16* src = A + (size_t)(m0 + (q >> 6)) * K + s * 32 + ((q & 63) >> 1);
      __builtin_amdgcn_global_load_lds(
          (const __attribute__((address_space(1))) void*)src,
          (__attribute__((address_space(3))) void*)&lds[buf][wid * 1024], 16, 0, 0);
    }
    {                                             // B tile: 16 KB, 1 load/thread
      int p = tid * 16;
      int q = bank_swz(p);
      const bf16* src = Bt + (size_t)(n0 + (q >> 6)) * K + s * 32 + ((q & 63) >> 1);
      __builtin_amdgcn_global_load_lds(
          (const __attribute__((address_space(1))) void*)src,
          (__attribute__((address_space(3))) void*)&lds[buf][16384 + wid * 1024], 16, 0, 0);
    }
  };

  auto rdA = [&](int buf, int row) -> bf16x8 {
    int off = bank_swz(row * 64 + gq * 16);
    return *reinterpret_cast<const bf16x8*>(&lds[buf][off]);
  };
  auto rdB = [&](int buf, int row) -> bf16x8 {
    int off = bank_swz(row * 64 + gq * 16);
    return *reinterpret_cast<const bf16x8*>(&lds[buf][16384 + off]);
  };

  // prologue: tiles 0 (buf0) and 1 (buf1); 2 loads/thread each.
  // vmcnt(2): tile0's 2 loads landed, tile1's may stay in flight.
  stage(0, 0); stage(1, 1);
  asm volatile("s_waitcnt vmcnt(2)" ::: "memory");
  __builtin_amdgcn_s_barrier();

  int bufr = 0;
  for (int t = 0; t < nt; ++t) {
#pragma unroll
    for (int mf = 0; mf < 4; ++mf) a[mf] = rdA(bufr, wr * 64 + mf * 16 + lr);
#pragma unroll
    for (int nf = 0; nf < 4; ++nf) b[nf] = rdB(bufr, wc * 64 + nf * 16 + lr);
    const bool st = (t + 2 < nt);
    int bufw = bufr + 2; if (bufw >= 3) bufw -= 3;
    if (st) stage(t + 2, bufw);                   // writes buf (t-1)%3: reads(t-1) done
    __builtin_amdgcn_s_setprio(1);
#pragma unroll
    for (int mf = 0; mf < 4; ++mf)
#pragma unroll
      for (int nf = 0; nf < 4; ++nf)
        acc[mf][nf] = MFMA_BF16_16x16x32(a[mf], b[nf], acc[mf][nf], 0, 0, 0);
    __builtin_amdgcn_s_setprio(0);
    asm volatile("s_waitcnt lgkmcnt(0)" ::: "memory");   // already 0; fences DS sinking
    if (st) asm volatile("s_waitcnt vmcnt(2)" ::: "memory");  // tile t+1 landed (counted)
    else    asm volatile("s_waitcnt vmcnt(0)" ::: "memory");  // tail drain
    __builtin_amdgcn_s_barrier();                 // single barrier per step
    bufr = bufr + 1; if (bufr >= 3) bufr -= 3;
  }

  // epilogue: per-wave 64x64
#pragma unroll
  for (int mf = 0; mf < 4; ++mf) {
#pragma unroll
    for (int nf = 0; nf < 4; ++nf) {
      int col = n0 + wc * 64 + nf * 16 + lr;
      float bv = __bfloat162float(bias[col]);
#pragma unroll
      for (int r = 0; r < 4; ++r) {
        int row = m0 + wr * 64 + mf * 16 + gq * 4 + r;
        float v = acc[mf][nf][r] + bv;
        if (EPI == 1) v = fmaxf(v, 0.0f);
        if (EPI == 2) v += __bfloat162float(res[(size_t)row * N + col]);
        C[(size_t)row * N + col] = __float2bfloat16(v);
      }
    }
  }
}

// ---------------- attention: 1 block per (local) batch, wave w does heads 2w, 2w+1 ----------------
__global__ __launch_bounds__(256)
void attn_kernel(const bf16* __restrict__ qkv, const bf16* __restrict__ cw,
                 bf16* __restrict__ ctx, float* __restrict__ attn_out) {
  __shared__ __align__(16) unsigned short qkv_lds[16][1544];
  __shared__ __align__(16) unsigned short p_lds[4][16][16];
  __shared__ float att_lds[4][16][16];
  const int b = blockIdx.x;
  const int tid = threadIdx.x, lane = tid & 63, w = tid >> 6;
  const int lr = lane & 15, g = lane >> 4;
  const bf16* src = qkv + (size_t)b * 16 * 1536;
  for (int t = tid; t < 16 * 192; t += 256) {
    int row = t / 192, ch = t - row * 192;
    *reinterpret_cast<bf16x8*>(&qkv_lds[row][ch * 8]) =
        *reinterpret_cast<const bf16x8*>(src + (size_t)row * 1536 + ch * 8);
  }
  __syncthreads();
  float attacc[4] = {0.f, 0.f, 0.f, 0.f};

  for (int hh = 0; hh < 2; ++hh) {
    const int h = w * 2 + hh;
    const unsigned short* qp = &qkv_lds[lr][h * 64 + g * 8];
    const unsigned short* kp = qp + 512;
    bf16x8 q0 = *reinterpret_cast<const bf16x8*>(qp);
    bf16x8 q1 = *reinterpret_cast<const bf16x8*>(qp + 32);
    bf16x8 k0 = *reinterpret_cast<const bf16x8*>(kp);
    bf16x8 k1 = *reinterpret_cast<const bf16x8*>(kp + 32);
    f32x4 s = {0.f, 0.f, 0.f, 0.f};
    s = MFMA_BF16_16x16x32(q0, k0, s, 0, 0, 0);
    s = MFMA_BF16_16x16x32(q1, k1, s, 0, 0, 0);
    float wgt = __bfloat162float(cw[h]);
    float p[4];
#pragma unroll
    for (int r = 0; r < 4; ++r) {
      float sv = s[r] * 0.125f;
      float mx = sv;
#pragma unroll
      for (int mm = 1; mm < 16; mm <<= 1) mx = fmaxf(mx, __shfl_xor(mx, mm, 16));
      float e = expf(sv - mx);
      float sm = e;
#pragma unroll
      for (int mm = 1; mm < 16; mm <<= 1) sm += __shfl_xor(sm, mm, 16);
      p[r] = e / sm;
      attacc[r] += wgt * p[r];
    }
#pragma unroll
    for (int r = 0; r < 4; ++r) p_lds[w][g * 4 + r][lr] = (unsigned short)f2bits(p[r]);
    __syncthreads();
    bf16x8 pa;
#pragma unroll
    for (int j = 0; j < 8; ++j) pa[j] = 0;
    if (g < 2) pa = *reinterpret_cast<const bf16x8*>(&p_lds[w][lr][g * 8]);
#pragma unroll
    for (int n = 0; n < 4; ++n) {
      bf16x8 vb;
#pragma unroll
      for (int j = 0; j < 8; ++j) vb[j] = 0;
      if (g < 2) {
#pragma unroll
        for (int j = 0; j < 8; ++j)
          vb[j] = (short)qkv_lds[g * 8 + j][1024 + h * 64 + n * 16 + lr];
      }
      f32x4 z = {0.f, 0.f, 0.f, 0.f};
      f32x4 d = MFMA_BF16_16x16x32(pa, vb, z, 0, 0, 0);
#pragma unroll
      for (int r = 0; r < 4; ++r)
        ctx[(size_t)(b * 16 + g * 4 + r) * 512 + h * 64 + n * 16 + lr] = __float2bfloat16(d[r]);
    }
    __syncthreads();
  }
#pragma unroll
  for (int r = 0; r < 4; ++r) att_lds[w][g * 4 + r][lr] = attacc[r];
  __syncthreads();
  const int q = tid >> 4, kk = tid & 15;
  float ssum = att_lds[0][q][kk] + att_lds[1][q][kk] + att_lds[2][q][kk] + att_lds[3][q][kk];
  attn_out[(size_t)b * 256 + q * 16 + kk] = ssum;
}

// ---------------- LayerNorm rows of 512, one wave per row; F32OUT selects output dtype ----------------
template <int F32OUT>
__global__ __launch_bounds__(256, 4)
void ln_kernel(const bf16* in, const bf16* __restrict__ gw,
               const bf16* __restrict__ bw, void* out) {
  const int row = blockIdx.x * 4 + (threadIdx.x >> 6);
  const int lane = threadIdx.x & 63;
  const bf16* rp = in + (size_t)row * 512 + lane * 8;
  bf16x8 xv = *reinterpret_cast<const bf16x8*>(rp);
  float xf[8];
#pragma unroll
  for (int j = 0; j < 8; ++j) xf[j] = bits2f(xv[j]);
  float s = 0.f;
#pragma unroll
  for (int j = 0; j < 8; ++j) s += xf[j];
#pragma unroll
  for (int o = 32; o >= 1; o >>= 1) s += __shfl_xor(s, o, 64);
  float mu = s * (1.0f / 512.0f);
  float v = 0.f;
#pragma unroll
  for (int j = 0; j < 8; ++j) { float d = xf[j] - mu; v += d * d; }
#pragma unroll
  for (int o = 32; o >= 1; o >>= 1) v += __shfl_xor(v, o, 64);
  float rs = rsqrtf(v * (1.0f / 512.0f) + 1e-5f);
  bf16x8 gv = *reinterpret_cast<const bf16x8*>(gw + lane * 8);
  bf16x8 bv = *reinterpret_cast<const bf16x8*>(bw + lane * 8);
  if (F32OUT) {
    float* op = (float*)out + (size_t)row * 512 + lane * 8;
    f32x4 o0, o1;
#pragma unroll
    for (int j = 0; j < 4; ++j) {
      o0[j] = (xf[j] - mu) * rs * bits2f(gv[j]) + bits2f(bv[j]);
      o1[j] = (xf[4 + j] - mu) * rs * bits2f(gv[4 + j]) + bits2f(bv[4 + j]);
    }
    *reinterpret_cast<f32x4*>(op) = o0;
    *reinterpret_cast<f32x4*>(op + 4) = o1;
  } else {
    bf16x8 o8;
#pragma unroll
    for (int j = 0; j < 8; ++j)
      o8[j] = f2bits((xf[j] - mu) * rs * bits2f(gv[j]) + bits2f(bv[j]));
    *reinterpret_cast<bf16x8*>((bf16*)out + (size_t)row * 512 + lane * 8) = o8;
  }
}

extern "C" void kernel_launch(void* const* d_in, const int* in_sizes, int n_in,
                              void* d_out, int out_size, void* d_ws, size_t ws_size,
                              hipStream_t stream) {
  const void* enc  = d_in[0];
  const void* wq   = d_in[1];
  const void* bq   = d_in[2];
  const void* wk   = d_in[3];
  const void* bk   = d_in[4];
  const void* wv   = d_in[5];
  const void* bvv  = d_in[6];
  const void* wo   = d_in[7];
  const void* bo   = d_in[8];
  const void* ln1g = d_in[9];
  const void* ln1b = d_in[10];
  const void* w1   = d_in[11];
  const void* b1   = d_in[12];
  const void* w2   = d_in[13];
  const void* b2   = d_in[14];
  const void* ln2g = d_in[15];
  const void* ln2b = d_in[16];
  const void* cw   = d_in[17];

  float* outp     = (float*)d_out;                       // f32 output
  float* attn_out = outp + (size_t)33554432;             // 4096*16*512

  char* wsp = (char*)d_ws;
  size_t off = 0;
  auto alloc = [&](size_t bytes) {
    void* p = wsp + off;
    off = (off + bytes + 255) & ~(size_t)255;
    return p;
  };
  int*  flag  = (int*)alloc(4);
  float* pe   = (float*)alloc((size_t)16 * 512 * 4);
  bf16* wqkvT = (bf16*)alloc((size_t)1536 * 512 * 2);
  bf16* woT   = (bf16*)alloc((size_t)512 * 512 * 2);
  bf16* w1T   = (bf16*)alloc((size_t)2048 * 512 * 2);
  bf16* w2T   = (bf16*)alloc((size_t)512 * 2048 * 2);
  bf16* bqkv  = (bf16*)alloc((size_t)1536 * 2);
  bf16* bo_c  = (bf16*)alloc((size_t)512 * 2);
  bf16* b1_c  = (bf16*)alloc((size_t)2048 * 2);
  bf16* b2_c  = (bf16*)alloc((size_t)512 * 2);
  bf16* l1g_c = (bf16*)alloc((size_t)512 * 2);
  bf16* l1b_c = (bf16*)alloc((size_t)512 * 2);
  bf16* l2g_c = (bf16*)alloc((size_t)512 * 2);
  bf16* l2b_c = (bf16*)alloc((size_t)512 * 2);
  bf16* cw_c  = (bf16*)alloc((size_t)8 * 2);
  size_t fixed_bytes = off;

  int CH = 1024;
  {
    const int cands[6] = {65536, 32768, 16384, 8192, 4096, 2048};
    for (int ci = 0; ci < 6; ++ci) {
      size_t need = fixed_bytes + (size_t)cands[ci] * 6144 + (1u << 20);
      if (need <= ws_size) { CH = cands[ci]; break; }
    }
  }
  bf16* x_c   = (bf16*)alloc((size_t)CH * 512 * 2);
  bf16* ctx_c = (bf16*)alloc((size_t)CH * 512 * 2);   // doubles as y after O-proj
  bf16* share = (bf16*)alloc((size_t)CH * 2048 * 2);  // qkv (CH*1536) then h (CH*2048)
  bf16* qkv = share;
  bf16* h   = share;
  bf16* y_c = ctx_c;

  detect_kernel<<<1, 256, 0, stream>>>((const unsigned short*)wq, flag);
  pe_kernel<<<16, 256, 0, stream>>>(pe);
  {
    TArgs ta;
    ta.seg[0] = {wq, (unsigned short*)wqkvT,               512,  512,    0};
    ta.seg[1] = {wk, (unsigned short*)(wqkvT + 512 * 512), 512,  512,  256};
    ta.seg[2] = {wv, (unsigned short*)(wqkvT + 1024 * 512),512,  512,  512};
    ta.seg[3] = {wo, (unsigned short*)woT,                 512,  512,  768};
    ta.seg[4] = {w1, (unsigned short*)w1T,                 512, 2048, 1024};
    ta.seg[5] = {w2, (unsigned short*)w2T,                2048,  512, 2048};
    ta.nseg = 6;
    transpose_all_kernel<<<3072, 256, 0, stream>>>(ta, flag);
  }
  {
    SmallCvtArgs a;
    a.seg[0]  = {bq,   bqkv,        512};
    a.seg[1]  = {bk,   bqkv + 512,  512};
    a.seg[2]  = {bvv,  bqkv + 1024, 512};
    a.seg[3]  = {bo,   bo_c,        512};
    a.seg[4]  = {b1,   b1_c,       2048};
    a.seg[5]  = {b2,   b2_c,        512};
    a.seg[6]  = {ln1g, l1g_c,       512};
    a.seg[7]  = {ln1b, l1b_c,       512};
    a.seg[8]  = {ln2g, l2g_c,       512};
    a.seg[9]  = {ln2b, l2b_c,       512};
    a.seg[10] = {cw,   cw_c,          8};
    small_cvt_kernel<<<11, 256, 0, stream>>>(a, flag);
  }

  for (int r0 = 0; r0 < 65536; r0 += CH) {
    float* out_c = outp + (size_t)r0 * 512;
    float* ao_c  = attn_out + (size_t)(r0 / 16) * 256;
    add_pe2_kernel<<<CH / 4, 256, 0, stream>>>(
        (const void*)((const bf16*)enc + (size_t)r0 * 512),
        (const void*)((const float*)enc + (size_t)r0 * 512), pe, x_c, flag);
    // QKV projection: [CH,512] @ [512,1536]
    gemm19_kernel<0><<<(CH / 256) * 6, 1024, 0, stream>>>(x_c, wqkvT, bqkv, nullptr, qkv, CH, 1536, 512);
    // attention + conv_att (attn_out in f32)
    attn_kernel<<<CH / 16, 256, 0, stream>>>(qkv, cw_c, ctx_c, ao_c);
    // O-proj + bias + residual(x), in-place over x -> preLN1
    gemm19_kernel<2><<<(CH / 256) * 2, 1024, 0, stream>>>(ctx_c, woT, bo_c, x_c, x_c, CH, 512, 512);
    // LN1: x -> y (bf16, reuses ctx buffer)
    ln_kernel<0><<<CH / 4, 256, 0, stream>>>(x_c, l1g_c, l1b_c, y_c);
    // FFN1 + relu
    gemm19_kernel<1><<<(CH / 256) * 8, 1024, 0, stream>>>(y_c, w1T, b1_c, nullptr, h, CH, 2048, 512);
    // FFN2 + bias + residual(y), in-place over y -> preLN2
    gemm19_kernel<2><<<(CH / 256) * 2, 1024, 0, stream>>>(h, w2T, b2_c, y_c, y_c, CH, 512, 2048);
    // LN2 -> f32 d_out rows
    ln_kernel<1><<<CH / 4, 256, 0, stream>>>(y_c, l2g_c, l2b_c, out_c);
  }
}